// Round 21
// baseline (705.833 us; speedup 1.0000x reference)
//
#include <hip/hip_runtime.h>
#include <stdint.h>

#define M_DIM 8192
#define N_DIM 11008
#define K_DIM 4096

#define BM 256
#define BN 256
#define BK 64                    // i8: 64 B per row per tile
#define NT (K_DIM / BK)          // 64 K-tiles
#define GRID_M (M_DIM / BM)      // 32
#define GRID_N (N_DIM / BN)      // 43
#define NWG (GRID_M * GRID_N)    // 1376 (divisible by 8)

#define BUFA 16384               // A tile-buffer (256 rows x 64 B)
#define NRING 4                  // ring-4 A-only: LDS = 64 KiB

typedef int i32x4 __attribute__((ext_vector_type(4)));

__device__ __forceinline__ void gload16(const int8_t* src, int8_t* dst) {
    __builtin_amdgcn_global_load_lds(
        (const __attribute__((address_space(1))) uint32_t*)src,
        (__attribute__((address_space(3))) uint32_t*)dst, 16, 0, 0);
}

// ---------- merged pre-pass ----------
// blocks [0,2048):  per-row absmax quant of x -> i8 + inv scale
// blocks [2048,4096): sign(w) -> i8 REPACKED INTO FRAGMENT ORDER:
//   chunk c = ((bn*4+wc)*4+n)*64 + t   (bn<43, wc<4, n<4, t<64)
//   lane l of chunk holds w[col = bn*256+wc*64+n*16+(l&15)]
//                          [k   = t*64 + (l>>4)*16 .. +16]  as 16 i8
//   -> a B-fragment load in the GEMM is ONE fully-coalesced dwordx4/wave.
// 44032 chunks x 64 lanes = 2.818M lane-tasks, grid-stride.

__global__ __launch_bounds__(256) void prepass_kernel(
    const float* __restrict__ x, int8_t* __restrict__ xq, float* __restrict__ sinv,
    const float* __restrict__ w, int8_t* __restrict__ wq)
{
    if (blockIdx.x < 2048) {
        const int wave = blockIdx.x * 4 + (threadIdx.x >> 6);
        const int lane = threadIdx.x & 63;
        const float* row = x + (size_t)wave * K_DIM;

        float4 v[16];
        float mx = 0.0f;
        #pragma unroll
        for (int j = 0; j < 16; ++j) {
            v[j] = *(const float4*)(row + (j * 64 + lane) * 4);
            mx = fmaxf(mx, fmaxf(fmaxf(fabsf(v[j].x), fabsf(v[j].y)),
                                 fmaxf(fabsf(v[j].z), fabsf(v[j].w))));
        }
        #pragma unroll
        for (int off = 32; off > 0; off >>= 1)
            mx = fmaxf(mx, __shfl_xor(mx, off));
        if (mx < 1e-30f) mx = 1e-30f;
        const float s = 127.0f / mx;

        int8_t* orow = xq + (size_t)wave * K_DIM;
        #pragma unroll
        for (int j = 0; j < 16; ++j) {
            int a = (int)__builtin_rintf(v[j].x * s);
            int b = (int)__builtin_rintf(v[j].y * s);
            int c = (int)__builtin_rintf(v[j].z * s);
            int d = (int)__builtin_rintf(v[j].w * s);
            uint32_t p = (uint32_t)(a & 0xFF) | ((uint32_t)(b & 0xFF) << 8) |
                         ((uint32_t)(c & 0xFF) << 16) | ((uint32_t)(d & 0xFF) << 24);
            *(uint32_t*)(orow + (j * 64 + lane) * 4) = p;
        }
        if (lane == 0) sinv[wave] = mx / 127.0f;
    } else {
        const long long total = 44032LL * 64;     // lane-tasks
        long long gi = (long long)(blockIdx.x - 2048) * blockDim.x + threadIdx.x;
        const long long stride = 2048LL * blockDim.x;
        for (; gi < total; gi += stride) {
            const int lane  = (int)(gi & 63);
            const long long chunk = gi >> 6;
            const int t  = (int)(chunk & 63);
            const int n  = (int)((chunk >> 6) & 3);
            const int wc = (int)((chunk >> 8) & 3);
            const int bn = (int)(chunk >> 10);
            const int col = bn * 256 + wc * 64 + n * 16 + (lane & 15);
            const int kb  = t * 64 + (lane >> 4) * 16;
            const float* src = w + (size_t)col * K_DIM + kb;
            uint32_t pk[4];
            #pragma unroll
            for (int q = 0; q < 4; ++q) {
                float4 f = *(const float4*)(src + q * 4);
                int a = (f.x > 0.f) ? 1 : ((f.x < 0.f) ? -1 : 0);
                int b = (f.y > 0.f) ? 1 : ((f.y < 0.f) ? -1 : 0);
                int c = (f.z > 0.f) ? 1 : ((f.z < 0.f) ? -1 : 0);
                int d = (f.w > 0.f) ? 1 : ((f.w < 0.f) ? -1 : 0);
                pk[q] = (uint32_t)(a & 0xFF) | ((uint32_t)(b & 0xFF) << 8) |
                        ((uint32_t)(c & 0xFF) << 16) | ((uint32_t)(d & 0xFF) << 24);
            }
            *(i32x4*)(wq + chunk * 1024 + lane * 16) =
                (i32x4){(int)pk[0], (int)pk[1], (int)pk[2], (int)pk[3]};
        }
    }
}

// ---------- main GEMM (i8): 256x256, BK=64, 16 waves, A-only LDS ring-4,
// B-FRAGS DIRECT FROM GLOBAL (repacked layout). r20 box analysis: LDS port
// (160 KB/tile) was the floor. Now: LDS = A 64KB reads + 16KB DMA = 940 cy;
// B = 64KB/tile/CU via VMEM/L2 (coalesced 1KB loads, ~1140 cy, parallel
// pipe); MFMA 1306 cy -> compute-bound target.
// bm-MINOR swizzle: 32 concurrent blocks per XCD share one 1MB B-panel
// (fits 4MB L2/XCD); A loses L2 reuse -> ~1.4GB HBM (~4.5 TB/s, under peak).
//
// body(t): br[n] x4 plain global loads (compiler-tracked waits; its counted
//   vmcnt remains correct with our untracked DMAs interleaved: in-order
//   oldest-first drain can only over-drain); ar[m] x4 ds_reads (compiler
//   lgkm); stageA(t+3) -> slot (t-1)&3 (WAR: readers done pre-boundary(t-1));
//   16 MFMA; boundary vmcnt + barrier.
// Boundary vmcnt (my DMAs only reach here; bf(t) consumed by MFMA(t)):
//   outstanding stages = {stA(t+1), stA(t+2), stA(t+3)} -> vmcnt(2) certifies
//   stA(t+1) (in-order: <=2 remaining => stA(t+1) done). Tail: NT-3 -> 1,
//   else 0. Prologue: stage 0,1,2; vmcnt(2); barrier.

__global__ __launch_bounds__(1024, 4) void ternary_gemm_i8(
    const int8_t* __restrict__ A, const int8_t* __restrict__ Bq,
    const float* __restrict__ bias, const float* __restrict__ sinv,
    float* __restrict__ out)
{
    extern __shared__ int8_t lds[];
    int8_t* As = lds;                   // [NRING][BUFA]

    const int tid  = threadIdx.x;
    const int lane = tid & 63;
    const int wid  = tid >> 6;        // 0..15
    const int wr   = wid >> 2;        // 0..3  (64-row slab)
    const int wc   = wid & 3;         // 0..3  (64-col slab)
    const int l15  = lane & 15;
    const int l4   = lane >> 4;       // 0..3

    // T1: bijective XCD swizzle, bm-MINOR (consecutive swz share bn -> B-panel
    // hot in the XCD's L2; required for the B-direct path)
    const int bid = blockIdx.x;
    const int swz = (bid & 7) * (NWG / 8) + (bid >> 3);
    const int bm  = swz % GRID_M;
    const int bn  = swz / GRID_M;
    const long brow = (long)bm * BM;
    const long bcol = (long)bn * BN;

    // ---- A staging addressing (r16-identical): row = tid>>2, LDS dest linear
    // (tid*16 over 16KB), global src slot inverse-swizzled ----
    const int rowt = tid >> 2;                        // 0..255
    const int ssrc = (tid & 3) ^ ((tid >> 3) & 3);
    const int8_t* pA = A + (size_t)(brow + rowt) * K_DIM + ssrc * 16;

    auto stageA = [&](int t, int bslot) {
        gload16(pA + (size_t)t * BK, As + bslot * BUFA + tid * 16);
    };

    // ---- A fragment read addressing (r16-verified swizzle) ----
    const int slot = l4 ^ ((l15 >> 1) & 3);
    const int aOff = (wr * 64 + l15) * 64 + slot * 16;   // + m*1024

    // ---- B fragment bases: repacked chunk (bn,wc,n,t), lane-contiguous ----
    const int8_t* pBn[4];
    #pragma unroll
    for (int n = 0; n < 4; ++n)
        pBn[n] = Bq + ((((size_t)bn * 4 + wc) * 4 + n) * 64) * 1024 + (size_t)lane * 16;

    i32x4 acc[4][4];
    #pragma unroll
    for (int m = 0; m < 4; ++m)
        #pragma unroll
        for (int n = 0; n < 4; ++n) acc[m][n] = (i32x4){0, 0, 0, 0};

    // ---- prologue: stage A tiles 0,1,2; vmcnt(2) [stA(0) landed]; barrier ----
    stageA(0, 0); stageA(1, 1); stageA(2, 2);
    asm volatile("s_waitcnt vmcnt(2)" ::: "memory");
    __builtin_amdgcn_s_barrier();
    __builtin_amdgcn_sched_barrier(0);

    for (int t = 0; t < NT; ++t) {
        const int b = t & 3;

        // B-frags: 4 coalesced global loads (compiler-tracked)
        i32x4 br[4];
        #pragma unroll
        for (int n = 0; n < 4; ++n)
            br[n] = *(const i32x4*)(pBn[n] + (size_t)t * 1024);

        // A-frags: 4 ds_reads (compiler lgkm before MFMA)
        i32x4 ar[4];
        #pragma unroll
        for (int m = 0; m < 4; ++m)
            ar[m] = *(const i32x4*)(As + b * BUFA + m * 1024 + aOff);

        // stage A(t+3) -> slot (t-1)&3
        if (t + 3 < NT) stageA(t + 3, (t + 3) & 3);

        __builtin_amdgcn_s_setprio(1);
        #pragma unroll
        for (int m = 0; m < 4; ++m)
            #pragma unroll
            for (int n = 0; n < 4; ++n)
                acc[m][n] = __builtin_amdgcn_mfma_i32_16x16x64_i8(ar[m], br[n], acc[m][n], 0, 0, 0);
        __builtin_amdgcn_s_setprio(0);
        __builtin_amdgcn_sched_barrier(0);

        // boundary: certify stA(t+1) + barrier
        if (t <= NT - 4)      { asm volatile("s_waitcnt vmcnt(2)" ::: "memory"); }
        else if (t == NT - 3) { asm volatile("s_waitcnt vmcnt(1)" ::: "memory"); }
        else                  { asm volatile("s_waitcnt vmcnt(0)" ::: "memory"); }
        __builtin_amdgcn_s_barrier();
        __builtin_amdgcn_sched_barrier(0);
    }

    // ---- epilogue: out = acc * sinv[row] + bias[col] ----
    // C/D layout (dtype-independent, m121-128): col=lane&15, row=(lane>>4)*4+reg
    int   cols[4];
    float bv[4];
    #pragma unroll
    for (int n = 0; n < 4; ++n) {
        cols[n] = (int)bcol + wc * 64 + n * 16 + l15;
        bv[n] = bias[cols[n]];
    }
    #pragma unroll
    for (int m = 0; m < 4; ++m) {
        const size_t row0 = (size_t)brow + wr * 64 + m * 16 + l4 * 4;
        float s0 = sinv[row0], s1 = sinv[row0 + 1], s2 = sinv[row0 + 2], s3 = sinv[row0 + 3];
        #pragma unroll
        for (int n = 0; n < 4; ++n) {
            out[(row0 + 0) * N_DIM + cols[n]] = (float)acc[m][n][0] * s0 + bv[n];
            out[(row0 + 1) * N_DIM + cols[n]] = (float)acc[m][n][1] * s1 + bv[n];
            out[(row0 + 2) * N_DIM + cols[n]] = (float)acc[m][n][2] * s2 + bv[n];
            out[(row0 + 3) * N_DIM + cols[n]] = (float)acc[m][n][3] * s3 + bv[n];
        }
    }
}

// ---------- fallback (only if workspace too small): correct but slow ----------

__global__ void naive_kernel(const float* __restrict__ x, const float* __restrict__ w,
                             const float* __restrict__ bias, float* __restrict__ out) {
    long long o = (long long)blockIdx.x * blockDim.x + threadIdx.x;
    if (o >= (long long)M_DIM * N_DIM) return;
    int row = (int)(o / N_DIM), col = (int)(o % N_DIM);
    float s = 0.0f;
    const float* xr = x + (size_t)row * K_DIM;
    const float* wr = w + (size_t)col * K_DIM;
    for (int k = 0; k < K_DIM; ++k) {
        float wv = wr[k];
        s += (wv > 0.0f) ? xr[k] : ((wv < 0.0f) ? -xr[k] : 0.0f);
    }
    out[o] = s + bias[col];
}

// ---------- launch ----------

extern "C" void kernel_launch(void* const* d_in, const int* in_sizes, int n_in,
                              void* d_out, int out_size, void* d_ws, size_t ws_size,
                              hipStream_t stream) {
    const float* x    = (const float*)d_in[0];
    const float* w    = (const float*)d_in[1];
    const float* bias = (const float*)d_in[2];
    float* out        = (float*)d_out;

    const size_t xq_bytes = (size_t)M_DIM * K_DIM;        // 33.6 MB
    const size_t wq_bytes = 44032ULL * 1024;              // 45.1 MB (repacked)
    const size_t si_bytes = (size_t)M_DIM * sizeof(float);

    if (ws_size >= xq_bytes + wq_bytes + si_bytes) {
        int8_t* xq   = (int8_t*)d_ws;
        int8_t* wq   = (int8_t*)((char*)d_ws + xq_bytes);
        float*  sinv = (float*)((char*)d_ws + xq_bytes + wq_bytes);

        prepass_kernel<<<4096, 256, 0, stream>>>(x, xq, sinv, w, wq);

        const int lds_bytes = NRING * BUFA;   // 65536
        hipFuncSetAttribute(reinterpret_cast<const void*>(ternary_gemm_i8),
                            hipFuncAttributeMaxDynamicSharedMemorySize, lds_bytes);
        ternary_gemm_i8<<<NWG, 1024, lds_bytes, stream>>>(xq, wq, bias, sinv, out);
    } else {
        const long long total = (long long)M_DIM * N_DIM;
        naive_kernel<<<(int)((total + 255) / 256), 256, 0, stream>>>(x, w, bias, out);
    }
}

// Round 22
// 464.154 us; speedup vs baseline: 1.5207x; 1.5207x over previous
//
#include <hip/hip_runtime.h>
#include <stdint.h>

#define M_DIM 8192
#define N_DIM 11008
#define K_DIM 4096

#define BM 256
#define BN 256
#define BK 64                    // i8: 64 B per row per tile
#define NT (K_DIM / BK)          // 64 K-tiles
#define GRID_M (M_DIM / BM)      // 32
#define GRID_N (N_DIM / BN)      // 43
#define NWG (GRID_M * GRID_N)    // 1376 (divisible by 8)

#define BUF (BM * BK)            // 16384 B per tile-buffer per matrix
#define NRING 4                  // ring-4: LDS = 4*2*16384 = 131072 B (128 KiB)

typedef int i32x4 __attribute__((ext_vector_type(4)));

__device__ __forceinline__ void gload16(const int8_t* src, int8_t* dst) {
    __builtin_amdgcn_global_load_lds(
        (const __attribute__((address_space(1))) uint32_t*)src,
        (__attribute__((address_space(3))) uint32_t*)dst, 16, 0, 0);
}

// ---------- merged pre-pass: one launch, two jobs (r20-verified) ----------
// blocks [0, 2048):   per-row absmax quant of x -> i8 + inv scale
// blocks [2048, 4096): f32 w -> sign(w) in i8 (grid-stride)

__global__ __launch_bounds__(256) void prepass_kernel(
    const float* __restrict__ x, int8_t* __restrict__ xq, float* __restrict__ sinv,
    const float* __restrict__ w, int8_t* __restrict__ wq, long long n16)
{
    if (blockIdx.x < 2048) {
        const int wave = blockIdx.x * 4 + (threadIdx.x >> 6);
        const int lane = threadIdx.x & 63;
        const float* row = x + (size_t)wave * K_DIM;

        float4 v[16];
        float mx = 0.0f;
        #pragma unroll
        for (int j = 0; j < 16; ++j) {
            v[j] = *(const float4*)(row + (j * 64 + lane) * 4);
            mx = fmaxf(mx, fmaxf(fmaxf(fabsf(v[j].x), fabsf(v[j].y)),
                                 fmaxf(fabsf(v[j].z), fabsf(v[j].w))));
        }
        #pragma unroll
        for (int off = 32; off > 0; off >>= 1)
            mx = fmaxf(mx, __shfl_xor(mx, off));
        if (mx < 1e-30f) mx = 1e-30f;
        const float s = 127.0f / mx;

        int8_t* orow = xq + (size_t)wave * K_DIM;
        #pragma unroll
        for (int j = 0; j < 16; ++j) {
            int a = (int)__builtin_rintf(v[j].x * s);
            int b = (int)__builtin_rintf(v[j].y * s);
            int c = (int)__builtin_rintf(v[j].z * s);
            int d = (int)__builtin_rintf(v[j].w * s);
            uint32_t p = (uint32_t)(a & 0xFF) | ((uint32_t)(b & 0xFF) << 8) |
                         ((uint32_t)(c & 0xFF) << 16) | ((uint32_t)(d & 0xFF) << 24);
            *(uint32_t*)(orow + (j * 64 + lane) * 4) = p;
        }
        if (lane == 0) sinv[wave] = mx / 127.0f;
    } else {
        long long i = (long long)(blockIdx.x - 2048) * blockDim.x + threadIdx.x;
        const long long stride = 2048LL * blockDim.x;
        for (; i < n16; i += stride) {
            const float* src = w + i * 16;
            uint32_t pk[4];
            #pragma unroll
            for (int q = 0; q < 4; ++q) {
                float4 f = *(const float4*)(src + q * 4);
                int a = (f.x > 0.f) ? 1 : ((f.x < 0.f) ? -1 : 0);
                int b = (f.y > 0.f) ? 1 : ((f.y < 0.f) ? -1 : 0);
                int c = (f.z > 0.f) ? 1 : ((f.z < 0.f) ? -1 : 0);
                int d = (f.w > 0.f) ? 1 : ((f.w < 0.f) ? -1 : 0);
                pk[q] = (uint32_t)(a & 0xFF) | ((uint32_t)(b & 0xFF) << 8) |
                        ((uint32_t)(c & 0xFF) << 16) | ((uint32_t)(d & 0xFF) << 24);
            }
            *(i32x4*)(wq + i * 16) = (i32x4){(int)pk[0], (int)pk[1], (int)pk[2], (int)pk[3]};
        }
    }
}

// ---------- main GEMM (i8): 256x256, BK=64, 16 waves, RING-4 (r16/r20 proven
// best: 386us GEMM, 0 conflicts, absmax 3.75, 4 waves/SIMD).
// Constraint-box (r8-r21, 14 variants): VRF 512 regs/SIMD pins geometry:
//   4 waves/SIMD -> <=128 regs -> 64x64/wave -> 4x LDS amplification ->
//   DS leg 1536 cy/tile > MFMA 1306 -> LDS-port-bound (2412 cy/tile, partial
//   overlap). 2 waves/SIMD -> amp-3 compute-bound but overlap fails (6
//   schedule variants incl. manual asm waits: all ~2500). B off LDS:
//   latency-bound (r12, r21). 32x32 shape: conflicts (r18). Super-tile: null
//   (r19). This kernel is the family's measured optimum.

__global__ __launch_bounds__(1024, 4) void ternary_gemm_i8(
    const int8_t* __restrict__ A, const int8_t* __restrict__ B,
    const float* __restrict__ bias, const float* __restrict__ sinv,
    float* __restrict__ out)
{
    extern __shared__ int8_t lds[];
    int8_t* As = lds;                   // [NRING][BUF]
    int8_t* Bs = lds + NRING * BUF;     // [NRING][BUF]

    const int tid  = threadIdx.x;
    const int lane = tid & 63;
    const int wid  = tid >> 6;        // 0..15
    const int wr   = wid >> 2;        // 0..3  (64-row slab)
    const int wc   = wid & 3;         // 0..3  (64-col slab)
    const int l15  = lane & 15;
    const int l4   = lane >> 4;       // 0..3

    // T1: bijective XCD swizzle (NWG % 8 == 0), bn-minor for A-panel L2 reuse
    const int bid = blockIdx.x;
    const int swz = (bid & 7) * (NWG / 8) + (bid >> 3);
    const int bm  = swz / GRID_N;
    const int bn  = swz % GRID_N;
    const long brow = (long)bm * BM;
    const long bcol = (long)bn * BN;

    // ---- staging addressing: 1024 threads cover 256 rows x 4 slots;
    // row = tid>>2, LDS dest linear (tid*16), global src slot inverse-swizzled
    const int rowt = tid >> 2;                        // 0..255
    const int ssrc = (tid & 3) ^ ((tid >> 3) & 3);
    const int8_t* pA = A + (size_t)(brow + rowt) * K_DIM + ssrc * 16;
    const int8_t* pB = B + (size_t)(bcol + rowt) * K_DIM + ssrc * 16;

    auto stageAB = [&](int t, int bslot) {
        gload16(pA + (size_t)t * BK, As + bslot * BUF + tid * 16);
        gload16(pB + (size_t)t * BK, Bs + bslot * BUF + tid * 16);
    };

    // ---- fragment read addressing (r6-verified swizzle) ----
    const int slot = l4 ^ ((l15 >> 1) & 3);
    const int aOff = (wr * 64 + l15) * 64 + slot * 16;   // + m*1024 (m*16 rows)
    const int bOff = (wc * 64 + l15) * 64 + slot * 16;   // + n*1024

    i32x4 acc[4][4];
    #pragma unroll
    for (int m = 0; m < 4; ++m)
        #pragma unroll
        for (int n = 0; n < 4; ++n) acc[m][n] = (i32x4){0, 0, 0, 0};

    // ---- prologue: stage tiles 0,1,2; vmcnt(4) [tile 0 landed]; barrier ----
    stageAB(0, 0); stageAB(1, 1); stageAB(2, 2);
    asm volatile("s_waitcnt vmcnt(4)" ::: "memory");
    __builtin_amdgcn_s_barrier();
    __builtin_amdgcn_sched_barrier(0);

    for (int t = 0; t < NT; ++t) {
        const int b = t & 3;

        // 8 frag reads, consumption order: br[0..3] then ar[0..3]
        i32x4 ar[4], br[4];
        #pragma unroll
        for (int n = 0; n < 4; ++n)
            br[n] = *(const i32x4*)(Bs + b * BUF + n * 1024 + bOff);
        #pragma unroll
        for (int m = 0; m < 4; ++m)
            ar[m] = *(const i32x4*)(As + b * BUF + m * 1024 + aOff);

        // stage(t+3) -> slot (t-1)%4 (WAR-safe: readers done pre-boundary(t-1))
        if (t + 3 < NT) stageAB(t + 3, (t + 3) & 3);

        __builtin_amdgcn_s_setprio(1);
        #pragma unroll
        for (int m = 0; m < 4; ++m)
            #pragma unroll
            for (int n = 0; n < 4; ++n)
                acc[m][n] = __builtin_amdgcn_mfma_i32_16x16x64_i8(ar[m], br[n], acc[m][n], 0, 0, 0);
        __builtin_amdgcn_s_setprio(0);
        __builtin_amdgcn_sched_barrier(0);

        // boundary: vmcnt ladder (certify tile t+1) + barrier
        if (t <= NT - 4)      { asm volatile("s_waitcnt vmcnt(4)" ::: "memory"); }
        else if (t == NT - 3) { asm volatile("s_waitcnt vmcnt(2)" ::: "memory"); }
        else                  { asm volatile("s_waitcnt vmcnt(0)" ::: "memory"); }
        __builtin_amdgcn_s_barrier();
        __builtin_amdgcn_sched_barrier(0);
    }

    // ---- epilogue: out = acc * sinv[row] + bias[col] ----
    // C/D layout (dtype-independent, m121-128): col=lane&15, row=(lane>>4)*4+reg
    int   cols[4];
    float bv[4];
    #pragma unroll
    for (int n = 0; n < 4; ++n) {
        cols[n] = (int)bcol + wc * 64 + n * 16 + l15;
        bv[n] = bias[cols[n]];
    }
    #pragma unroll
    for (int m = 0; m < 4; ++m) {
        const size_t row0 = (size_t)brow + wr * 64 + m * 16 + l4 * 4;
        float s0 = sinv[row0], s1 = sinv[row0 + 1], s2 = sinv[row0 + 2], s3 = sinv[row0 + 3];
        #pragma unroll
        for (int n = 0; n < 4; ++n) {
            out[(row0 + 0) * N_DIM + cols[n]] = (float)acc[m][n][0] * s0 + bv[n];
            out[(row0 + 1) * N_DIM + cols[n]] = (float)acc[m][n][1] * s1 + bv[n];
            out[(row0 + 2) * N_DIM + cols[n]] = (float)acc[m][n][2] * s2 + bv[n];
            out[(row0 + 3) * N_DIM + cols[n]] = (float)acc[m][n][3] * s3 + bv[n];
        }
    }
}

// ---------- fallback (only if workspace too small): correct but slow ----------

__global__ void naive_kernel(const float* __restrict__ x, const float* __restrict__ w,
                             const float* __restrict__ bias, float* __restrict__ out) {
    long long o = (long long)blockIdx.x * blockDim.x + threadIdx.x;
    if (o >= (long long)M_DIM * N_DIM) return;
    int row = (int)(o / N_DIM), col = (int)(o % N_DIM);
    float s = 0.0f;
    const float* xr = x + (size_t)row * K_DIM;
    const float* wr = w + (size_t)col * K_DIM;
    for (int k = 0; k < K_DIM; ++k) {
        float wv = wr[k];
        s += (wv > 0.0f) ? xr[k] : ((wv < 0.0f) ? -xr[k] : 0.0f);
    }
    out[o] = s + bias[col];
}

// ---------- launch ----------

extern "C" void kernel_launch(void* const* d_in, const int* in_sizes, int n_in,
                              void* d_out, int out_size, void* d_ws, size_t ws_size,
                              hipStream_t stream) {
    const float* x    = (const float*)d_in[0];
    const float* w    = (const float*)d_in[1];
    const float* bias = (const float*)d_in[2];
    float* out        = (float*)d_out;

    const size_t xq_bytes = (size_t)M_DIM * K_DIM;        // 33.6 MB
    const size_t wq_bytes = (size_t)N_DIM * K_DIM;        // 45.1 MB
    const size_t si_bytes = (size_t)M_DIM * sizeof(float);

    if (ws_size >= xq_bytes + wq_bytes + si_bytes) {
        int8_t* xq   = (int8_t*)d_ws;
        int8_t* wq   = (int8_t*)((char*)d_ws + xq_bytes);
        float*  sinv = (float*)((char*)d_ws + xq_bytes + wq_bytes);

        const long long n16 = ((long long)N_DIM * K_DIM) / 16;
        prepass_kernel<<<4096, 256, 0, stream>>>(x, xq, sinv, w, wq, n16);

        const int lds_bytes = NRING * 2 * BUF;   // 131072
        hipFuncSetAttribute(reinterpret_cast<const void*>(ternary_gemm_i8),
                            hipFuncAttributeMaxDynamicSharedMemorySize, lds_bytes);
        ternary_gemm_i8<<<NWG, 1024, lds_bytes, stream>>>(xq, wq, bias, sinv, out);
    } else {
        const long long total = (long long)M_DIM * N_DIM;
        naive_kernel<<<(int)((total + 255) / 256), 256, 0, stream>>>(x, w, bias, out);
    }
}